// Round 1
// baseline (735.282 us; speedup 1.0000x reference)
//
#include <hip/hip_runtime.h>

#define SCAN_B 1024

// ---------------- precompute kernels ----------------

__global__ void zero2_kernel(int* __restrict__ a, int* __restrict__ b, int n) {
  int i = blockIdx.x * blockDim.x + threadIdx.x;
  if (i < n) { a[i] = 0; b[i] = 0; }
}

// cnt[d] = number of real edges with dst == d
__global__ void count_kernel(const int* __restrict__ ei, int* __restrict__ cnt, int E) {
  int i = blockIdx.x * blockDim.x + threadIdx.x;
  if (i < E) atomicAdd(&cnt[ei[E + i]], 1);
}

// dinv[n] = rsqrt(deg) with deg = cnt + 1 (self loop) — always > 0
__global__ void dinv_kernel(const int* __restrict__ cnt, float* __restrict__ dinv, int n) {
  int i = blockIdx.x * blockDim.x + threadIdx.x;
  if (i < n) dinv[i] = rsqrtf((float)(cnt[i] + 1));
}

__global__ void scan1_kernel(const int* __restrict__ cnt, int* __restrict__ rowstart,
                             int* __restrict__ bsum, int n) {
  __shared__ int sm[SCAN_B];
  const int t = threadIdx.x;
  const int i = blockIdx.x * SCAN_B + t;
  int v = (i < n) ? cnt[i] : 0;
  sm[t] = v;
  __syncthreads();
  for (int off = 1; off < SCAN_B; off <<= 1) {
    int x = (t >= off) ? sm[t - off] : 0;
    __syncthreads();
    if (t >= off) sm[t] += x;
    __syncthreads();
  }
  if (i < n) rowstart[i] = sm[t] - v;       // block-local exclusive
  if (t == SCAN_B - 1) bsum[blockIdx.x] = sm[t];
}

__global__ void scan2_kernel(int* __restrict__ bsum, int nb) {
  __shared__ int sm[SCAN_B];
  const int t = threadIdx.x;
  int v = (t < nb) ? bsum[t] : 0;
  sm[t] = v;
  __syncthreads();
  for (int off = 1; off < SCAN_B; off <<= 1) {
    int x = (t >= off) ? sm[t - off] : 0;
    __syncthreads();
    if (t >= off) sm[t] += x;
    __syncthreads();
  }
  if (t < nb) bsum[t] = sm[t] - v;          // exclusive block offsets
}

__global__ void scan3_kernel(int* __restrict__ rowstart, const int* __restrict__ bsum, int n) {
  int i = blockIdx.x * blockDim.x + threadIdx.x;
  if (i < n) rowstart[i] += bsum[i / SCAN_B];
}

// CSR fill: col[rowstart[d] .. ] = src list of node d (order irrelevant for a sum)
__global__ void fill_kernel(const int* __restrict__ ei, int* __restrict__ fillc,
                            const int* __restrict__ rowstart, int* __restrict__ col, int E) {
  int e = blockIdx.x * blockDim.x + threadIdx.x;
  if (e < E) {
    int s = ei[e];
    int d = ei[E + e];
    int p = atomicAdd(&fillc[d], 1);
    col[rowstart[d] + p] = s;
  }
}

// ---------------- fp32 tiled GEMM: C[M x N] = A[M x K] @ B[K x N], BN == N ----------------

template <int BM, int BN, int BK, int TM, int TN>
__global__ void __launch_bounds__((BM / TM) * (BN / TN))
gemm_kernel(const float* __restrict__ A, const float* __restrict__ B,
            float* __restrict__ C, int M, int K, int N) {
  constexpr int NT  = (BM / TM) * (BN / TN);
  constexpr int LDA = BM + 4;   // +4 floats keeps 16B alignment, spreads banks
  constexpr int LDB = BN + 4;
  __shared__ float As[BK][LDA];
  __shared__ float Bs[BK][LDB];

  const int tid = threadIdx.x;
  const int tx  = tid % (BN / TN);
  const int ty  = tid / (BN / TN);
  const int m0  = blockIdx.x * BM;

  // A loader: float4 over K; B loader: float4 over N
  constexpr int AKT   = BK / 4;
  constexpr int AROWS = NT / AKT;
  constexpr int APASS = BM / AROWS;
  const int a_r = tid / AKT;
  const int a_k = (tid % AKT) * 4;
  constexpr int BNT   = BN / 4;
  constexpr int BROWS = NT / BNT;
  constexpr int BPASS = BK / BROWS;
  const int b_n = (tid % BNT) * 4;
  const int b_k = tid / BNT;

  float acc[TM][TN] = {};

  for (int k0 = 0; k0 < K; k0 += BK) {
#pragma unroll
    for (int p = 0; p < APASS; ++p) {
      const int r  = a_r + p * AROWS;
      const int gm = m0 + r;
      float4 v = make_float4(0.f, 0.f, 0.f, 0.f);
      if (gm < M) v = *(const float4*)&A[(size_t)gm * K + k0 + a_k];
      As[a_k + 0][r] = v.x;
      As[a_k + 1][r] = v.y;
      As[a_k + 2][r] = v.z;
      As[a_k + 3][r] = v.w;
    }
#pragma unroll
    for (int p = 0; p < BPASS; ++p) {
      const int r = b_k + p * BROWS;
      *(float4*)&Bs[r][b_n] = *(const float4*)&B[(size_t)(k0 + r) * N + b_n];
    }
    __syncthreads();
#pragma unroll
    for (int kk = 0; kk < BK; ++kk) {
      float a[TM], b[TN];
#pragma unroll
      for (int i = 0; i < TM; i += 4) *(float4*)&a[i] = *(const float4*)&As[kk][ty * TM + i];
#pragma unroll
      for (int j = 0; j < TN; j += 4) *(float4*)&b[j] = *(const float4*)&Bs[kk][tx * TN + j];
#pragma unroll
      for (int i = 0; i < TM; ++i)
#pragma unroll
        for (int j = 0; j < TN; ++j) acc[i][j] = fmaf(a[i], b[j], acc[i][j]);
    }
    __syncthreads();
  }

#pragma unroll
  for (int i = 0; i < TM; ++i) {
    const int gm = m0 + ty * TM + i;
    if (gm < M) {
#pragma unroll
      for (int j = 0; j < TN; j += 4)
        *(float4*)&C[(size_t)gm * N + tx * TN + j] = *(const float4*)&acc[i][j];
    }
  }
}

// ---------------- CSR pull aggregation: out[n] = relu(sum_{s in N(n)} h[s]*dinv[s]*dinv[n] + h[n]*dinv[n]^2 + bias) ----------------

template <int F>
__global__ void agg_kernel(const float* __restrict__ hin, const int* __restrict__ rowstart,
                           const int* __restrict__ cnt, const int* __restrict__ col,
                           const float* __restrict__ dinv, const float* __restrict__ bias,
                           float* __restrict__ outp, int N) {
  constexpr int VPL = F / 64;  // floats per lane (2 for F=128, 1 for F=64)
  const int wave = (int)((blockIdx.x * (size_t)blockDim.x + threadIdx.x) >> 6);
  const int lane = threadIdx.x & 63;
  if (wave >= N) return;
  const int n   = wave;
  const float dn = dinv[n];

  float acc[VPL];
  if constexpr (VPL == 2) {
    float2 hv = *(const float2*)&hin[(size_t)n * F + lane * 2];
    acc[0] = hv.x * (dn * dn);
    acc[1] = hv.y * (dn * dn);
  } else {
    acc[0] = hin[(size_t)n * F + lane] * (dn * dn);
  }

  const int beg = rowstart[n];
  const int end = beg + cnt[n];
  for (int j = beg; j < end; ++j) {
    const int s = col[j];
    const float w = dinv[s] * dn;
    if constexpr (VPL == 2) {
      float2 v = *(const float2*)&hin[(size_t)s * F + lane * 2];
      acc[0] = fmaf(v.x, w, acc[0]);
      acc[1] = fmaf(v.y, w, acc[1]);
    } else {
      acc[0] = fmaf(hin[(size_t)s * F + lane], w, acc[0]);
    }
  }

  if constexpr (VPL == 2) {
    float2 bb = *(const float2*)&bias[lane * 2];
    float2 r;
    r.x = fmaxf(acc[0] + bb.x, 0.f);
    r.y = fmaxf(acc[1] + bb.y, 0.f);
    *(float2*)&outp[(size_t)n * F + lane * 2] = r;
  } else {
    outp[(size_t)n * F + lane] = fmaxf(acc[0] + bias[lane], 0.f);
  }
}

// ---------------- launch ----------------

extern "C" void kernel_launch(void* const* d_in, const int* in_sizes, int n_in,
                              void* d_out, int out_size, void* d_ws, size_t ws_size,
                              hipStream_t stream) {
  const float* x  = (const float*)d_in[0];
  const int*   ei = (const int*)d_in[1];   // [2, E]; harness materializes integers as int32
  const float* W1 = (const float*)d_in[2];
  const float* b1 = (const float*)d_in[3];
  const float* W2 = (const float*)d_in[4];
  const float* b2 = (const float*)d_in[5];
  float* out = (float*)d_out;

  const int F1 = in_sizes[3];           // 128
  const int F2 = in_sizes[5];           // 64
  const int F0 = in_sizes[2] / F1;      // 512
  const int N  = in_sizes[0] / F0;      // 100000
  const int E  = in_sizes[1] / 2;       // 1600000

  char* ws = (char*)d_ws;
  size_t off = 0;
  auto alloc = [&](size_t bytes) -> void* {
    void* p = ws + off;
    off = (off + bytes + 255) & ~(size_t)255;
    return p;
  };

  int*   cnt      = (int*)alloc((size_t)N * 4);
  int*   fillc    = (int*)alloc((size_t)N * 4);
  int*   rowstart = (int*)alloc((size_t)N * 4);
  float* dinv     = (float*)alloc((size_t)N * 4);
  const int nb    = (N + SCAN_B - 1) / SCAN_B;
  int*   bsum     = (int*)alloc((size_t)nb * 4);
  int*   col      = (int*)alloc((size_t)E * 4);
  float* h        = (float*)alloc((size_t)N * F1 * 4);
  float* h1       = (float*)alloc((size_t)N * F1 * 4);
  float* h2       = h;  // h dead after agg1 — reuse for layer-2 GEMM output

  // graph precompute
  zero2_kernel<<<(N + 255) / 256, 256, 0, stream>>>(cnt, fillc, N);
  count_kernel<<<(E + 255) / 256, 256, 0, stream>>>(ei, cnt, E);
  dinv_kernel<<<(N + 255) / 256, 256, 0, stream>>>(cnt, dinv, N);
  scan1_kernel<<<nb, SCAN_B, 0, stream>>>(cnt, rowstart, bsum, N);
  scan2_kernel<<<1, SCAN_B, 0, stream>>>(bsum, nb);
  scan3_kernel<<<(N + 255) / 256, 256, 0, stream>>>(rowstart, bsum, N);
  fill_kernel<<<(E + 255) / 256, 256, 0, stream>>>(ei, fillc, rowstart, col, E);

  // layer 1
  gemm_kernel<128, 128, 16, 8, 8><<<(N + 127) / 128, 256, 0, stream>>>(x, W1, h, N, F0, F1);
  {
    const long waves = N;
    const long blocks = (waves * 64 + 255) / 256;
    agg_kernel<128><<<(int)blocks, 256, 0, stream>>>(h, rowstart, cnt, col, dinv, b1, h1, N);
  }

  // layer 2
  gemm_kernel<128, 64, 16, 8, 8><<<(N + 127) / 128, 128, 0, stream>>>(h1, W2, h2, N, F1, F2);
  {
    const long waves = N;
    const long blocks = (waves * 64 + 255) / 256;
    agg_kernel<64><<<(int)blocks, 256, 0, stream>>>(h2, rowstart, cnt, col, dinv, b2, out, N);
  }
}

// Round 2
// 633.631 us; speedup vs baseline: 1.1604x; 1.1604x over previous
//
#include <hip/hip_runtime.h>

#define SCAN_B 1024

// ---------------- precompute kernels ----------------

__global__ void zero2_kernel(int* __restrict__ a, int* __restrict__ b, int n) {
  int i = blockIdx.x * blockDim.x + threadIdx.x;
  if (i < n) { a[i] = 0; b[i] = 0; }
}

__global__ void count_kernel(const int* __restrict__ ei, int* __restrict__ cnt, int E) {
  int i = blockIdx.x * blockDim.x + threadIdx.x;
  if (i < E) atomicAdd(&cnt[ei[E + i]], 1);
}

__global__ void dinv_kernel(const int* __restrict__ cnt, float* __restrict__ dinv, int n) {
  int i = blockIdx.x * blockDim.x + threadIdx.x;
  if (i < n) dinv[i] = rsqrtf((float)(cnt[i] + 1));
}

__global__ void scan1_kernel(const int* __restrict__ cnt, int* __restrict__ rowstart,
                             int* __restrict__ bsum, int n) {
  __shared__ int sm[SCAN_B];
  const int t = threadIdx.x;
  const int i = blockIdx.x * SCAN_B + t;
  int v = (i < n) ? cnt[i] : 0;
  sm[t] = v;
  __syncthreads();
  for (int off = 1; off < SCAN_B; off <<= 1) {
    int x = (t >= off) ? sm[t - off] : 0;
    __syncthreads();
    if (t >= off) sm[t] += x;
    __syncthreads();
  }
  if (i < n) rowstart[i] = sm[t] - v;
  if (t == SCAN_B - 1) bsum[blockIdx.x] = sm[t];
}

__global__ void scan2_kernel(int* __restrict__ bsum, int nb) {
  __shared__ int sm[SCAN_B];
  const int t = threadIdx.x;
  int v = (t < nb) ? bsum[t] : 0;
  sm[t] = v;
  __syncthreads();
  for (int off = 1; off < SCAN_B; off <<= 1) {
    int x = (t >= off) ? sm[t - off] : 0;
    __syncthreads();
    if (t >= off) sm[t] += x;
    __syncthreads();
  }
  if (t < nb) bsum[t] = sm[t] - v;
}

__global__ void scan3_kernel(int* __restrict__ rowstart, const int* __restrict__ bsum, int n) {
  int i = blockIdx.x * blockDim.x + threadIdx.x;
  if (i < n) rowstart[i] += bsum[i / SCAN_B];
}

// CSR fill with packed per-edge weight: ew[j] = (src_as_float_bits, dinv[src]*dinv[dst])
__global__ void fill_kernel(const int* __restrict__ ei, int* __restrict__ fillc,
                            const int* __restrict__ rowstart, const float* __restrict__ dinv,
                            float2* __restrict__ ew, int E) {
  int e = blockIdx.x * blockDim.x + threadIdx.x;
  if (e < E) {
    int s = ei[e];
    int d = ei[E + e];
    int p = atomicAdd(&fillc[d], 1);
    ew[rowstart[d] + p] = make_float2(__int_as_float(s), dinv[s] * dinv[d]);
  }
}

// ---------------- fp32 tiled GEMM with reg-prefetch double buffer ----------------
// C[M x N] = A[M x K] @ B[K x N], BN == N (grid is 1-D over M, A read once).
// Wave lane map is 8x8 (tx,ty) so LDS frag reads are 8 addrs @32B stride = 2-way (free).

template <int BM, int BN, int BK, int TM, int TN>
__global__ void __launch_bounds__((BM / TM) * (BN / TN))
gemm_kernel(const float* __restrict__ A, const float* __restrict__ B,
            float* __restrict__ C, int M, int K, int N) {
  constexpr int NT  = (BM / TM) * (BN / TN);
  constexpr int LDA = BM + 4;
  constexpr int LDB = BN + 4;
  __shared__ float As[BK][LDA];
  __shared__ float Bs[BK][LDB];

  const int tid  = threadIdx.x;
  const int lane = tid & 63;
  const int wv   = tid >> 6;
  constexpr int WX = (BN / TN) / 8;   // waves tiled along x
  const int tx = (lane & 7) + (wv % WX) * 8;
  const int ty = (lane >> 3) + (wv / WX) * 8;
  const int m0 = blockIdx.x * BM;

  // A loader: float4 along K. B loader: float4 along N.
  constexpr int AKT   = BK / 4;
  constexpr int AROWS = NT / AKT;
  constexpr int APASS = BM / AROWS;
  const int a_r = tid / AKT;
  const int a_k = (tid % AKT) * 4;
  constexpr int BNT   = BN / 4;
  constexpr int BROWS = NT / BNT;
  constexpr int BPASS = BK / BROWS;
  const int b_n = (tid % BNT) * 4;
  const int b_k = tid / BNT;

  float4 ra[APASS], rb[BPASS];

  auto loadA = [&](int k0) {
#pragma unroll
    for (int p = 0; p < APASS; ++p) {
      const int gm = m0 + a_r + p * AROWS;
      ra[p] = (gm < M) ? *(const float4*)&A[(size_t)gm * K + k0 + a_k]
                       : make_float4(0.f, 0.f, 0.f, 0.f);
    }
  };
  auto loadB = [&](int k0) {
#pragma unroll
    for (int p = 0; p < BPASS; ++p)
      rb[p] = *(const float4*)&B[(size_t)(k0 + b_k + p * BROWS) * N + b_n];
  };

  float acc[TM][TN] = {};

  loadA(0);
  loadB(0);

  for (int k0 = 0; k0 < K; k0 += BK) {
    // regs -> LDS
#pragma unroll
    for (int p = 0; p < APASS; ++p) {
      const int r = a_r + p * AROWS;
      As[a_k + 0][r] = ra[p].x;
      As[a_k + 1][r] = ra[p].y;
      As[a_k + 2][r] = ra[p].z;
      As[a_k + 3][r] = ra[p].w;
    }
#pragma unroll
    for (int p = 0; p < BPASS; ++p)
      *(float4*)&Bs[b_k + p * BROWS][b_n] = rb[p];
    __syncthreads();

    // issue next tile's global loads early; they fly during the FMA loop
    if (k0 + BK < K) {
      loadA(k0 + BK);
      loadB(k0 + BK);
    }

#pragma unroll
    for (int kk = 0; kk < BK; ++kk) {
      float a[TM], b[TN];
#pragma unroll
      for (int i = 0; i < TM; i += 4) *(float4*)&a[i] = *(const float4*)&As[kk][ty * TM + i];
#pragma unroll
      for (int j = 0; j < TN; j += 4) *(float4*)&b[j] = *(const float4*)&Bs[kk][tx * TN + j];
#pragma unroll
      for (int i = 0; i < TM; ++i)
#pragma unroll
        for (int j = 0; j < TN; ++j) acc[i][j] = fmaf(a[i], b[j], acc[i][j]);
    }
    __syncthreads();
  }

#pragma unroll
  for (int i = 0; i < TM; ++i) {
    const int gm = m0 + ty * TM + i;
    if (gm < M) {
#pragma unroll
      for (int j = 0; j < TN; j += 4)
        *(float4*)&C[(size_t)gm * N + tx * TN + j] = *(const float4*)&acc[i][j];
    }
  }
}

// ---------------- CSR pull aggregation, packed (src,w) edges, 4x unrolled ----------------

template <int F>
__global__ void agg_kernel(const float* __restrict__ hin, const int* __restrict__ rowstart,
                           const int* __restrict__ cnt, const float2* __restrict__ ew,
                           const float* __restrict__ dinv, const float* __restrict__ bias,
                           float* __restrict__ outp, int N) {
  constexpr int VPL = F / 64;  // 2 for F=128, 1 for F=64
  const int wave = (int)((blockIdx.x * (size_t)blockDim.x + threadIdx.x) >> 6);
  const int lane = threadIdx.x & 63;
  if (wave >= N) return;
  const int n = wave;
  const float dn = dinv[n];

  float acc0 = 0.f, acc1 = 0.f;
  {
    const float w = dn * dn;  // self loop
    if constexpr (VPL == 2) {
      float2 hv = *(const float2*)&hin[(size_t)n * F + lane * 2];
      acc0 = hv.x * w;
      acc1 = hv.y * w;
    } else {
      acc0 = hin[(size_t)n * F + lane] * w;
    }
  }

  const int beg = rowstart[n];
  const int end = beg + cnt[n];
  int j = beg;
  for (; j + 4 <= end; j += 4) {
    float2 e0 = ew[j + 0], e1 = ew[j + 1], e2 = ew[j + 2], e3 = ew[j + 3];
    const int s0 = __float_as_int(e0.x), s1 = __float_as_int(e1.x);
    const int s2 = __float_as_int(e2.x), s3 = __float_as_int(e3.x);
    if constexpr (VPL == 2) {
      float2 v0 = *(const float2*)&hin[(size_t)s0 * F + lane * 2];
      float2 v1 = *(const float2*)&hin[(size_t)s1 * F + lane * 2];
      float2 v2 = *(const float2*)&hin[(size_t)s2 * F + lane * 2];
      float2 v3 = *(const float2*)&hin[(size_t)s3 * F + lane * 2];
      acc0 = fmaf(v0.x, e0.y, acc0); acc1 = fmaf(v0.y, e0.y, acc1);
      acc0 = fmaf(v1.x, e1.y, acc0); acc1 = fmaf(v1.y, e1.y, acc1);
      acc0 = fmaf(v2.x, e2.y, acc0); acc1 = fmaf(v2.y, e2.y, acc1);
      acc0 = fmaf(v3.x, e3.y, acc0); acc1 = fmaf(v3.y, e3.y, acc1);
    } else {
      float v0 = hin[(size_t)s0 * F + lane];
      float v1 = hin[(size_t)s1 * F + lane];
      float v2 = hin[(size_t)s2 * F + lane];
      float v3 = hin[(size_t)s3 * F + lane];
      acc0 = fmaf(v0, e0.y, acc0);
      acc0 = fmaf(v1, e1.y, acc0);
      acc0 = fmaf(v2, e2.y, acc0);
      acc0 = fmaf(v3, e3.y, acc0);
    }
  }
  for (; j < end; ++j) {
    float2 e = ew[j];
    const int s = __float_as_int(e.x);
    if constexpr (VPL == 2) {
      float2 v = *(const float2*)&hin[(size_t)s * F + lane * 2];
      acc0 = fmaf(v.x, e.y, acc0);
      acc1 = fmaf(v.y, e.y, acc1);
    } else {
      acc0 = fmaf(hin[(size_t)s * F + lane], e.y, acc0);
    }
  }

  if constexpr (VPL == 2) {
    float2 bb = *(const float2*)&bias[lane * 2];
    float2 r;
    r.x = fmaxf(acc0 + bb.x, 0.f);
    r.y = fmaxf(acc1 + bb.y, 0.f);
    *(float2*)&outp[(size_t)n * F + lane * 2] = r;
  } else {
    outp[(size_t)n * F + lane] = fmaxf(acc0 + bias[lane], 0.f);
  }
}

// ---------------- launch ----------------

extern "C" void kernel_launch(void* const* d_in, const int* in_sizes, int n_in,
                              void* d_out, int out_size, void* d_ws, size_t ws_size,
                              hipStream_t stream) {
  const float* x  = (const float*)d_in[0];
  const int*   ei = (const int*)d_in[1];
  const float* W1 = (const float*)d_in[2];
  const float* b1 = (const float*)d_in[3];
  const float* W2 = (const float*)d_in[4];
  const float* b2 = (const float*)d_in[5];
  float* out = (float*)d_out;

  const int F1 = in_sizes[3];           // 128
  const int F2 = in_sizes[5];           // 64
  const int F0 = in_sizes[2] / F1;      // 512
  const int N  = in_sizes[0] / F0;      // 100000
  const int E  = in_sizes[1] / 2;       // 1600000

  char* ws = (char*)d_ws;
  size_t off = 0;
  auto alloc = [&](size_t bytes) -> void* {
    void* p = ws + off;
    off = (off + bytes + 255) & ~(size_t)255;
    return p;
  };

  int*    cnt      = (int*)alloc((size_t)N * 4);
  int*    fillc    = (int*)alloc((size_t)N * 4);
  int*    rowstart = (int*)alloc((size_t)N * 4);
  float*  dinv     = (float*)alloc((size_t)N * 4);
  const int nb     = (N + SCAN_B - 1) / SCAN_B;
  int*    bsum     = (int*)alloc((size_t)nb * 4);
  float2* ew       = (float2*)alloc((size_t)E * 8);
  float*  h        = (float*)alloc((size_t)N * F1 * 4);
  float*  h1       = (float*)alloc((size_t)N * F1 * 4);
  float*  h2       = h;  // reuse

  zero2_kernel<<<(N + 255) / 256, 256, 0, stream>>>(cnt, fillc, N);
  count_kernel<<<(E + 255) / 256, 256, 0, stream>>>(ei, cnt, E);
  dinv_kernel<<<(N + 255) / 256, 256, 0, stream>>>(cnt, dinv, N);
  scan1_kernel<<<nb, SCAN_B, 0, stream>>>(cnt, rowstart, bsum, N);
  scan2_kernel<<<1, SCAN_B, 0, stream>>>(bsum, nb);
  scan3_kernel<<<(N + 255) / 256, 256, 0, stream>>>(rowstart, bsum, N);
  fill_kernel<<<(E + 255) / 256, 256, 0, stream>>>(ei, fillc, rowstart, dinv, ew, E);

  // layer 1: h = x@W1 ; h1 = relu(agg(h) + b1)
  gemm_kernel<128, 128, 32, 8, 8><<<(N + 127) / 128, 256, 0, stream>>>(x, W1, h, N, F0, F1);
  {
    const long blocks = ((long)N * 64 + 255) / 256;
    agg_kernel<128><<<(int)blocks, 256, 0, stream>>>(h, rowstart, cnt, ew, dinv, b1, h1, N);
  }

  // layer 2: h2 = h1@W2 ; out = relu(agg(h2) + b2)
  gemm_kernel<128, 64, 32, 8, 8><<<(N + 127) / 128, 128, 0, stream>>>(h1, W2, h2, N, F1, F2);
  {
    const long blocks = ((long)N * 64 + 255) / 256;
    agg_kernel<64><<<(int)blocks, 256, 0, stream>>>(h2, rowstart, cnt, ew, dinv, b2, out, N);
  }
}

// Round 3
// 473.477 us; speedup vs baseline: 1.5529x; 1.3383x over previous
//
#include <hip/hip_runtime.h>

#define SCAN_B 1024

using bf16x8 = __attribute__((ext_vector_type(8))) short;
using f32x4  = __attribute__((ext_vector_type(4))) float;
typedef unsigned short ushort4v __attribute__((ext_vector_type(4)));

// split fp32 into bf16 hi (truncation) + bf16 lo (RNE of exact remainder)
__device__ inline void split1(float x, unsigned short& h, unsigned short& l) {
  unsigned u  = __float_as_uint(x);
  unsigned hu = u & 0xFFFF0000u;
  float lo = x - __uint_as_float(hu);
  unsigned lu = __float_as_uint(lo);
  h = (unsigned short)(hu >> 16);
  l = (unsigned short)((lu + 0x7FFFu + ((lu >> 16) & 1u)) >> 16);
}

// ---------------- precompute kernels ----------------

__global__ void zero2_kernel(int* __restrict__ a, int* __restrict__ b, int n) {
  int i = blockIdx.x * blockDim.x + threadIdx.x;
  if (i < n) { a[i] = 0; b[i] = 0; }
}

__global__ void count_kernel(const int* __restrict__ ei, int* __restrict__ cnt, int E) {
  int i = blockIdx.x * blockDim.x + threadIdx.x;
  if (i < E) atomicAdd(&cnt[ei[E + i]], 1);
}

__global__ void dinv_kernel(const int* __restrict__ cnt, float* __restrict__ dinv, int n) {
  int i = blockIdx.x * blockDim.x + threadIdx.x;
  if (i < n) dinv[i] = rsqrtf((float)(cnt[i] + 1));
}

__global__ void scan1_kernel(const int* __restrict__ cnt, int* __restrict__ rowstart,
                             int* __restrict__ bsum, int n) {
  __shared__ int sm[SCAN_B];
  const int t = threadIdx.x;
  const int i = blockIdx.x * SCAN_B + t;
  int v = (i < n) ? cnt[i] : 0;
  sm[t] = v;
  __syncthreads();
  for (int off = 1; off < SCAN_B; off <<= 1) {
    int x = (t >= off) ? sm[t - off] : 0;
    __syncthreads();
    if (t >= off) sm[t] += x;
    __syncthreads();
  }
  if (i < n) rowstart[i] = sm[t] - v;
  if (t == SCAN_B - 1) bsum[blockIdx.x] = sm[t];
}

__global__ void scan2_kernel(int* __restrict__ bsum, int nb) {
  __shared__ int sm[SCAN_B];
  const int t = threadIdx.x;
  int v = (t < nb) ? bsum[t] : 0;
  sm[t] = v;
  __syncthreads();
  for (int off = 1; off < SCAN_B; off <<= 1) {
    int x = (t >= off) ? sm[t - off] : 0;
    __syncthreads();
    if (t >= off) sm[t] += x;
    __syncthreads();
  }
  if (t < nb) bsum[t] = sm[t] - v;
}

__global__ void scan3_kernel(int* __restrict__ rowstart, const int* __restrict__ bsum, int n) {
  int i = blockIdx.x * blockDim.x + threadIdx.x;
  if (i < n) rowstart[i] += bsum[i / SCAN_B];
}

__global__ void fill_kernel(const int* __restrict__ ei, int* __restrict__ fillc,
                            const int* __restrict__ rowstart, const float* __restrict__ dinv,
                            float2* __restrict__ ew, int E) {
  int e = blockIdx.x * blockDim.x + threadIdx.x;
  if (e < E) {
    int s = ei[e];
    int d = ei[E + e];
    int p = atomicAdd(&fillc[d], 1);
    ew[rowstart[d] + p] = make_float2(__int_as_float(s), dinv[s] * dinv[d]);
  }
}

// W [K][N] fp32 -> transposed split Wh/Wl [N][K] bf16 (k-contiguous for MFMA staging)
__global__ void wsplit_kernel(const float* __restrict__ W, unsigned short* __restrict__ Wh,
                              unsigned short* __restrict__ Wl, int K, int N) {
  int i = blockIdx.x * blockDim.x + threadIdx.x;
  if (i < K * N) {
    int k = i / N, n = i % N;
    unsigned short h, l;
    split1(W[i], h, l);
    Wh[(size_t)n * K + k] = h;
    Wl[(size_t)n * K + k] = l;
  }
}

// ---------------- split-bf16 MFMA GEMM ----------------
// C[M x N] = A[M x K] @ B[K x N], BN == N. A fp32 (split in-kernel),
// B pre-split/transposed: Wh/Wl [N][K] bf16. BK = 32. 256 threads = 4 waves (2x2).
// acc = Ah*Bh + Ah*Bl + Al*Bh  (al*bl dropped, ~2^-16)

template <int BM, int BN>
__global__ void __launch_bounds__(256)
gemm_mfma_kernel(const float* __restrict__ A, const unsigned short* __restrict__ Wh,
                 const unsigned short* __restrict__ Wl, float* __restrict__ C,
                 int M, int K) {
  constexpr int BK  = 32;
  constexpr int LDK = 40;               // bf16 elems per LDS row (80B: 16B-aligned, 20-bank stride)
  constexpr int MR  = BM / 2 / 16;      // 4
  constexpr int NR  = BN / 2 / 16;      // 4 (BN=128) or 2 (BN=64)
  constexpr int N   = BN;

  __shared__ __align__(16) unsigned short Ah[BM][LDK];
  __shared__ __align__(16) unsigned short Al[BM][LDK];
  __shared__ __align__(16) unsigned short Bh[BN][LDK];
  __shared__ __align__(16) unsigned short Bl[BN][LDK];

  const int tid  = threadIdx.x;
  const int lane = tid & 63;
  const int w    = tid >> 6;
  const int wm   = w >> 1;              // 0/1
  const int wn   = w & 1;               // 0/1
  const int fr   = lane & 15;
  const int fq   = lane >> 4;           // 0..3
  const int m0   = blockIdx.x * BM;

  // A loader map: 128 rows x 32 k -> thread covers (m = a_m + 32p, k chunk a_c*4)
  const int a_c = tid & 7;
  const int a_m = tid >> 3;

  f32x4 acc[MR][NR] = {};

  for (int kt = 0; kt < K; kt += BK) {
    // ---- global loads ----
    float4 av[4];
#pragma unroll
    for (int p = 0; p < 4; ++p) {
      const int gm = m0 + a_m + 32 * p;
      av[p] = (gm < M) ? *(const float4*)&A[(size_t)gm * K + kt + 4 * a_c]
                       : make_float4(0.f, 0.f, 0.f, 0.f);
    }

    __syncthreads();   // previous tile's LDS reads complete

    // ---- A: split + store ----
#pragma unroll
    for (int p = 0; p < 4; ++p) {
      const int r = a_m + 32 * p;
      ushort4v hv, lv;
      split1(av[p].x, ((unsigned short*)&hv)[0], ((unsigned short*)&lv)[0]);
      split1(av[p].y, ((unsigned short*)&hv)[1], ((unsigned short*)&lv)[1]);
      split1(av[p].z, ((unsigned short*)&hv)[2], ((unsigned short*)&lv)[2]);
      split1(av[p].w, ((unsigned short*)&hv)[3], ((unsigned short*)&lv)[3]);
      *(ushort4v*)((char*)&Ah[0][0] + r * (LDK * 2) + a_c * 8) = hv;
      *(ushort4v*)((char*)&Al[0][0] + r * (LDK * 2) + a_c * 8) = lv;
    }

    // ---- B: straight 16B copies (pre-split, k-contiguous) ----
#pragma unroll
    for (int idx = tid; idx < BN * 4; idx += 256) {
      const int r = idx >> 2, j = idx & 3;
      *(uint4*)((char*)&Bh[0][0] + r * (LDK * 2) + 16 * j) =
          *(const uint4*)&Wh[(size_t)r * K + kt + 8 * j];
      *(uint4*)((char*)&Bl[0][0] + r * (LDK * 2) + 16 * j) =
          *(const uint4*)&Wl[(size_t)r * K + kt + 8 * j];
    }

    __syncthreads();

    // ---- fragments + MFMA ----
    bf16x8 ah[MR], al[MR], bh[NR], bl[NR];
#pragma unroll
    for (int mi = 0; mi < MR; ++mi) {
      const char* p = (const char*)&Ah[0][0] + (wm * MR * 16 + mi * 16 + fr) * (LDK * 2) + fq * 16;
      const char* q = (const char*)&Al[0][0] + (wm * MR * 16 + mi * 16 + fr) * (LDK * 2) + fq * 16;
      ah[mi] = *(const bf16x8*)p;
      al[mi] = *(const bf16x8*)q;
    }
#pragma unroll
    for (int ni = 0; ni < NR; ++ni) {
      const char* p = (const char*)&Bh[0][0] + (wn * NR * 16 + ni * 16 + fr) * (LDK * 2) + fq * 16;
      const char* q = (const char*)&Bl[0][0] + (wn * NR * 16 + ni * 16 + fr) * (LDK * 2) + fq * 16;
      bh[ni] = *(const bf16x8*)p;
      bl[ni] = *(const bf16x8*)q;
    }
#pragma unroll
    for (int mi = 0; mi < MR; ++mi)
#pragma unroll
      for (int ni = 0; ni < NR; ++ni) {
        acc[mi][ni] = __builtin_amdgcn_mfma_f32_16x16x32_bf16(ah[mi], bh[ni], acc[mi][ni], 0, 0, 0);
        acc[mi][ni] = __builtin_amdgcn_mfma_f32_16x16x32_bf16(ah[mi], bl[ni], acc[mi][ni], 0, 0, 0);
        acc[mi][ni] = __builtin_amdgcn_mfma_f32_16x16x32_bf16(al[mi], bh[ni], acc[mi][ni], 0, 0, 0);
      }
  }

  // ---- store: C/D map col=lane&15, row=(lane>>4)*4+reg ----
#pragma unroll
  for (int mi = 0; mi < MR; ++mi) {
    const int rbase = m0 + wm * MR * 16 + mi * 16 + fq * 4;
#pragma unroll
    for (int ni = 0; ni < NR; ++ni) {
      const int col = wn * NR * 16 + ni * 16 + fr;
#pragma unroll
      for (int r = 0; r < 4; ++r) {
        const int gm = rbase + r;
        if (gm < M) C[(size_t)gm * N + col] = acc[mi][ni][r];
      }
    }
  }
}

// ---------------- CSR pull aggregation, packed (src,w) edges, 4x unrolled ----------------

template <int F>
__global__ void agg_kernel(const float* __restrict__ hin, const int* __restrict__ rowstart,
                           const int* __restrict__ cnt, const float2* __restrict__ ew,
                           const float* __restrict__ dinv, const float* __restrict__ bias,
                           float* __restrict__ outp, int N) {
  constexpr int VPL = F / 64;
  const int wave = (int)((blockIdx.x * (size_t)blockDim.x + threadIdx.x) >> 6);
  const int lane = threadIdx.x & 63;
  if (wave >= N) return;
  const int n = wave;
  const float dn = dinv[n];

  float acc0 = 0.f, acc1 = 0.f;
  {
    const float w = dn * dn;
    if constexpr (VPL == 2) {
      float2 hv = *(const float2*)&hin[(size_t)n * F + lane * 2];
      acc0 = hv.x * w;
      acc1 = hv.y * w;
    } else {
      acc0 = hin[(size_t)n * F + lane] * w;
    }
  }

  const int beg = rowstart[n];
  const int end = beg + cnt[n];
  int j = beg;
  for (; j + 4 <= end; j += 4) {
    float2 e0 = ew[j + 0], e1 = ew[j + 1], e2 = ew[j + 2], e3 = ew[j + 3];
    const int s0 = __float_as_int(e0.x), s1 = __float_as_int(e1.x);
    const int s2 = __float_as_int(e2.x), s3 = __float_as_int(e3.x);
    if constexpr (VPL == 2) {
      float2 v0 = *(const float2*)&hin[(size_t)s0 * F + lane * 2];
      float2 v1 = *(const float2*)&hin[(size_t)s1 * F + lane * 2];
      float2 v2 = *(const float2*)&hin[(size_t)s2 * F + lane * 2];
      float2 v3 = *(const float2*)&hin[(size_t)s3 * F + lane * 2];
      acc0 = fmaf(v0.x, e0.y, acc0); acc1 = fmaf(v0.y, e0.y, acc1);
      acc0 = fmaf(v1.x, e1.y, acc0); acc1 = fmaf(v1.y, e1.y, acc1);
      acc0 = fmaf(v2.x, e2.y, acc0); acc1 = fmaf(v2.y, e2.y, acc1);
      acc0 = fmaf(v3.x, e3.y, acc0); acc1 = fmaf(v3.y, e3.y, acc1);
    } else {
      float v0 = hin[(size_t)s0 * F + lane];
      float v1 = hin[(size_t)s1 * F + lane];
      float v2 = hin[(size_t)s2 * F + lane];
      float v3 = hin[(size_t)s3 * F + lane];
      acc0 = fmaf(v0, e0.y, acc0);
      acc0 = fmaf(v1, e1.y, acc0);
      acc0 = fmaf(v2, e2.y, acc0);
      acc0 = fmaf(v3, e3.y, acc0);
    }
  }
  for (; j < end; ++j) {
    float2 e = ew[j];
    const int s = __float_as_int(e.x);
    if constexpr (VPL == 2) {
      float2 v = *(const float2*)&hin[(size_t)s * F + lane * 2];
      acc0 = fmaf(v.x, e.y, acc0);
      acc1 = fmaf(v.y, e.y, acc1);
    } else {
      acc0 = fmaf(hin[(size_t)s * F + lane], e.y, acc0);
    }
  }

  if constexpr (VPL == 2) {
    float2 bb = *(const float2*)&bias[lane * 2];
    float2 r;
    r.x = fmaxf(acc0 + bb.x, 0.f);
    r.y = fmaxf(acc1 + bb.y, 0.f);
    *(float2*)&outp[(size_t)n * F + lane * 2] = r;
  } else {
    outp[(size_t)n * F + lane] = fmaxf(acc0 + bias[lane], 0.f);
  }
}

// ---------------- launch ----------------

extern "C" void kernel_launch(void* const* d_in, const int* in_sizes, int n_in,
                              void* d_out, int out_size, void* d_ws, size_t ws_size,
                              hipStream_t stream) {
  const float* x  = (const float*)d_in[0];
  const int*   ei = (const int*)d_in[1];
  const float* W1 = (const float*)d_in[2];
  const float* b1 = (const float*)d_in[3];
  const float* W2 = (const float*)d_in[4];
  const float* b2 = (const float*)d_in[5];
  float* out = (float*)d_out;

  const int F1 = in_sizes[3];           // 128
  const int F2 = in_sizes[5];           // 64
  const int F0 = in_sizes[2] / F1;      // 512
  const int N  = in_sizes[0] / F0;      // 100000
  const int E  = in_sizes[1] / 2;       // 1600000

  char* ws = (char*)d_ws;
  size_t off = 0;
  auto alloc = [&](size_t bytes) -> void* {
    void* p = ws + off;
    off = (off + bytes + 255) & ~(size_t)255;
    return p;
  };

  int*    cnt      = (int*)alloc((size_t)N * 4);
  int*    fillc    = (int*)alloc((size_t)N * 4);
  int*    rowstart = (int*)alloc((size_t)N * 4);
  float*  dinv     = (float*)alloc((size_t)N * 4);
  const int nb     = (N + SCAN_B - 1) / SCAN_B;
  int*    bsum     = (int*)alloc((size_t)nb * 4);
  float2* ew       = (float2*)alloc((size_t)E * 8);
  float*  h        = (float*)alloc((size_t)N * F1 * 4);
  float*  h1       = (float*)alloc((size_t)N * F1 * 4);
  float*  h2       = h;  // reuse
  unsigned short* W1h = (unsigned short*)alloc((size_t)F0 * F1 * 2);
  unsigned short* W1l = (unsigned short*)alloc((size_t)F0 * F1 * 2);
  unsigned short* W2h = (unsigned short*)alloc((size_t)F1 * F2 * 2);
  unsigned short* W2l = (unsigned short*)alloc((size_t)F1 * F2 * 2);

  zero2_kernel<<<(N + 255) / 256, 256, 0, stream>>>(cnt, fillc, N);
  count_kernel<<<(E + 255) / 256, 256, 0, stream>>>(ei, cnt, E);
  dinv_kernel<<<(N + 255) / 256, 256, 0, stream>>>(cnt, dinv, N);
  scan1_kernel<<<nb, SCAN_B, 0, stream>>>(cnt, rowstart, bsum, N);
  scan2_kernel<<<1, SCAN_B, 0, stream>>>(bsum, nb);
  scan3_kernel<<<(N + 255) / 256, 256, 0, stream>>>(rowstart, bsum, N);
  fill_kernel<<<(E + 255) / 256, 256, 0, stream>>>(ei, fillc, rowstart, dinv, ew, E);
  wsplit_kernel<<<(F0 * F1 + 255) / 256, 256, 0, stream>>>(W1, W1h, W1l, F0, F1);
  wsplit_kernel<<<(F1 * F2 + 255) / 256, 256, 0, stream>>>(W2, W2h, W2l, F1, F2);

  // layer 1: h = x@W1 ; h1 = relu(agg(h) + b1)
  gemm_mfma_kernel<128, 128><<<(N + 127) / 128, 256, 0, stream>>>(x, W1h, W1l, h, N, F0);
  {
    const long blocks = ((long)N * 64 + 255) / 256;
    agg_kernel<128><<<(int)blocks, 256, 0, stream>>>(h, rowstart, cnt, ew, dinv, b1, h1, N);
  }

  // layer 2: h2 = h1@W2 ; out = relu(agg(h2) + b2)
  gemm_mfma_kernel<128, 64><<<(N + 127) / 128, 256, 0, stream>>>(h1, W2h, W2l, h2, N, F1);
  {
    const long blocks = ((long)N * 64 + 255) / 256;
    agg_kernel<64><<<(int)blocks, 256, 0, stream>>>(h2, rowstart, cnt, ew, dinv, b2, out, N);
  }
}